// Round 14
// baseline (257.773 us; speedup 1.0000x reference)
//
#include <hip/hip_runtime.h>
#include <hip/hip_bf16.h>

// Problem constants (HyperGCNConv: N=100000, M=50000, K=8, DIN=DOUT=128)
#define NV 100000
#define ME 50000
#define NINC (ME * 8)                     // 400000 incidences
#define ECAP 32                           // fixed entry slots per vertex (P(deg>32)~1e-17)
constexpr float WMED = 1.0f / 13.0f;      // 1/(2K-3), K=8

typedef __attribute__((ext_vector_type(8))) short bf16x8;   // MFMA A/B frag
typedef __attribute__((ext_vector_type(4))) float f32x4;    // MFMA C/D frag

static __device__ inline void cvt_split8(const float4& a, const float4& b,
                                         bf16x8& hi, bf16x8& lo) {
    const float v[8] = {a.x, a.y, a.z, a.w, b.x, b.y, b.z, b.w};
    #pragma unroll
    for (int j = 0; j < 8; ++j) {
        __hip_bfloat16 h = __float2bfloat16(v[j]);
        const float hf = __bfloat162float(h);
        __hip_bfloat16 l = __float2bfloat16(v[j] - hf);
        union { __hip_bfloat16 b; short s; } uh{h}, ul{l};
        hi[j] = uh.s;
        lo[j] = ul.s;
    }
}

// ---------------- K1: Y = X @ W + b via split-bf16 MFMA (R14) --------------
// R14: revert to R5's in-kernel W staging (measured 44.2us, equal to the
// LDS-free+Wg version) so the k_winit pre-pass can be DELETED. Prologue also
// absorbs cnt/cur/deg init (391x512 threads >= NV, fire-and-forget stores).
// 3-term split (Xh*Wh + Xh*Wl + Xl*Wh) -> ~1e-5 rel err (argmax-safe).
// Hoisted 16 A-loads (R5): one latency wait, 16 loads in flight.
__global__ __launch_bounds__(512, 4) void k_gemm(const float* __restrict__ X,
                                                 const float* __restrict__ W,
                                                 const float* __restrict__ bias,
                                                 float* __restrict__ Y,
                                                 __hip_bfloat16* __restrict__ Ybf,
                                                 int* __restrict__ cnt,
                                                 int* __restrict__ cur,
                                                 float* __restrict__ deg) {
    __shared__ bf16x8 sWh[2048];   // frag (s*8+g)*64 + (q*16+m) -> W[32s+8q+j][16g+m]
    __shared__ bf16x8 sWl[2048];
    const int t = threadIdx.x;
    const int wv = t >> 6;         // wave 0..7 -> rows 32wv..32wv+31
    const int L  = t & 63;
    const int m  = L & 15;         // A row sel / B,C col sel
    const int q  = L >> 4;         // k-quad / C row-quad

    // ---- fused workspace init (was k_winit) ----
    const int gi = blockIdx.x * 512 + t;
    if (gi < NV) { cnt[gi] = 0; cur[gi] = 0; deg[gi] = 1.0f; }

    // ---- stage W split into LDS (one-time, all 512 threads; R5 verbatim) --
    for (int idx = t; idx < 128 * 32; idx += 512) {
        const int k  = idx >> 5;            // 0..127
        const int c4 = (idx & 31) * 4;      // col group
        const float4 w = *(const float4*)(W + (long)k * 128 + c4);
        const float wv4[4] = {w.x, w.y, w.z, w.w};
        short* swh = (short*)sWh;
        short* swl = (short*)sWl;
        const int s = k >> 5, qq = (k >> 3) & 3, j = k & 7;
        #pragma unroll
        for (int j2 = 0; j2 < 4; ++j2) {
            const int c = c4 + j2;
            const int frag = (s * 8 + (c >> 4)) * 64 + qq * 16 + (c & 15);
            __hip_bfloat16 h = __float2bfloat16(wv4[j2]);
            const float hf = __bfloat162float(h);
            __hip_bfloat16 l = __float2bfloat16(wv4[j2] - hf);
            union { __hip_bfloat16 b; short s; } uh{h}, ul{l};
            swh[frag * 8 + j] = uh.s;
            swl[frag * 8 + j] = ul.s;
        }
    }

    const int row_base = blockIdx.x * 256 + wv * 32;
    int r0 = row_base + m;      if (r0 > NV - 1) r0 = NV - 1;
    int r1 = row_base + 16 + m; if (r1 > NV - 1) r1 = NV - 1;
    const float* p0 = X + (long)r0 * 128 + q * 8;
    const float* p1 = X + (long)r1 * 128 + q * 8;

    // ---- hoisted A loads: 16 independent 16B loads, all in flight ----
    float4 A[4][4];
    #pragma unroll
    for (int s = 0; s < 4; ++s) {
        A[s][0] = *(const float4*)(p0 + s * 32);
        A[s][1] = *(const float4*)(p0 + s * 32 + 4);
        A[s][2] = *(const float4*)(p1 + s * 32);
        A[s][3] = *(const float4*)(p1 + s * 32 + 4);
    }
    __syncthreads();

    f32x4 acc[2][8];
    #pragma unroll
    for (int tt = 0; tt < 2; ++tt)
        #pragma unroll
        for (int g = 0; g < 8; ++g)
            acc[tt][g] = (f32x4){0.f, 0.f, 0.f, 0.f};

    #pragma unroll
    for (int s = 0; s < 4; ++s) {
        bf16x8 ah0, al0, ah1, al1;
        cvt_split8(A[s][0], A[s][1], ah0, al0);
        cvt_split8(A[s][2], A[s][3], ah1, al1);
        #pragma unroll
        for (int g = 0; g < 8; ++g) {
            const bf16x8 bh = sWh[(s * 8 + g) * 64 + L];
            const bf16x8 bl = sWl[(s * 8 + g) * 64 + L];
            acc[0][g] = __builtin_amdgcn_mfma_f32_16x16x32_bf16(ah0, bh, acc[0][g], 0, 0, 0);
            acc[0][g] = __builtin_amdgcn_mfma_f32_16x16x32_bf16(ah0, bl, acc[0][g], 0, 0, 0);
            acc[0][g] = __builtin_amdgcn_mfma_f32_16x16x32_bf16(al0, bh, acc[0][g], 0, 0, 0);
            acc[1][g] = __builtin_amdgcn_mfma_f32_16x16x32_bf16(ah1, bh, acc[1][g], 0, 0, 0);
            acc[1][g] = __builtin_amdgcn_mfma_f32_16x16x32_bf16(ah1, bl, acc[1][g], 0, 0, 0);
            acc[1][g] = __builtin_amdgcn_mfma_f32_16x16x32_bf16(al1, bh, acc[1][g], 0, 0, 0);
        }
    }

    // epilogue: C layout col=lane&15, row=quad*4+reg
    #pragma unroll
    for (int g = 0; g < 8; ++g) {
        const int col = g * 16 + m;
        const float bc = bias[col];
        #pragma unroll
        for (int tt = 0; tt < 2; ++tt) {
            #pragma unroll
            for (int r = 0; r < 4; ++r) {
                const int row = row_base + tt * 16 + q * 4 + r;
                const float v = acc[tt][g][r] + bc;
                const float vn = __shfl_xor(v, 1);   // neighbor col (lane pair)
                if (row < NV) {
                    Y[(long)row * 128 + col] = v;
                    if ((L & 1) == 0) {              // even lane stores packed pair
                        __hip_bfloat162 h2;
                        h2.x = __float2bfloat16(v);
                        h2.y = __float2bfloat16(vn);
                        *(__hip_bfloat162*)(Ybf + (long)row * 128 + col) = h2;
                    }
                }
            }
        }
    }
}

// ---------------- K2: per-hyperedge argmax pair (uvpos only) ----------------
// R10 structure kept: random-512B-gather bound (~2.5TB/s fabric, FETCH 93MB,
// floor ~42-48us -- implementation-insensitive, verified across 4 variants).
// Fused CSR histogram (R10) + fused deg atomics (R12) ride under the gather.
__global__ __launch_bounds__(256) void k_edge(const float* __restrict__ Y,
                                              const int* __restrict__ vertex,
                                              int* __restrict__ uvpos,
                                              int* __restrict__ cnt,
                                              float* __restrict__ deg) {
    __shared__ float sF[4][8 * 132];
    const int wid = threadIdx.x >> 6;
    const int lane = threadIdx.x & 63;
    const int m = blockIdx.x * 4 + wid;
    float* F = sF[wid];

    int verts[8];
    #pragma unroll
    for (int p = 0; p < 8; ++p) verts[p] = vertex[m * 8 + p];

    // fused histogram: one atomic per incidence, hidden under the row gather
    if (lane < 8) atomicAdd(cnt + vertex[m * 8 + lane], 1);

    #pragma unroll
    for (int p = 0; p < 8; ++p) {
        const float2 v = *(const float2*)(Y + (long)verts[p] * 128 + lane * 2);
        *(float2*)(F + p * 132 + lane * 2) = v;
    }
    __syncthreads();

    const int k = lane >> 3, l = lane & 7;
    float acc = 0.0f;
    const float4* ra = (const float4*)(F + k * 132);
    const float4* rb = (const float4*)(F + l * 132);
    #pragma unroll
    for (int d4 = 0; d4 < 32; ++d4) {
        const float4 a = ra[d4], b = rb[d4];
        acc = fmaf(a.x, b.x, acc);
        acc = fmaf(a.y, b.y, acc);
        acc = fmaf(a.z, b.z, acc);
        acc = fmaf(a.w, b.w, acc);
    }
    const float sqk = __shfl(acc, k * 9);
    const float sql = __shfl(acc, l * 9);
    float v = sqk + sql - 2.0f * acc;
    int idx = lane;
    #pragma unroll
    for (int off = 32; off >= 1; off >>= 1) {
        const float ov = __shfl_xor(v, off);
        const int oi = __shfl_xor(idx, off);
        if (ov > v || (ov == v && oi < idx)) { v = ov; idx = oi; }
    }
    if (lane == 0) uvpos[m] = idx;

    // fused degree: role by POSITION (matches ref's med mask semantics)
    if (lane < 8) {
        const int ui = idx >> 3, vi = idx & 7;
        const float w = (lane == ui || lane == vi) ? (7.0f * WMED) : (2.0f * WMED);
        atomicAdd(deg + vertex[m * 8 + lane], w);
    }
}

// ---------------- K4: per-edge w*S,w*P rows + fixed-slot entry fill --------
// R14: entries are fixed-slot [NV][ECAP] -- no scan, no rowptr. Lanes 0..7
// write this edge's 8 entries via atomic cursor `cur` (zeroed in k_gemm),
// hidden under the Ybf random-gather latency (R10/R12/R13 precedent).
__global__ __launch_bounds__(256) void k_sp(const __hip_bfloat16* __restrict__ Ybf,
                                            const int* __restrict__ vertex,
                                            const int* __restrict__ uvpos,
                                            const float* __restrict__ deg,
                                            int* __restrict__ cur,
                                            int* __restrict__ entries,
                                            __hip_bfloat162* __restrict__ SP) {
    const int wid = threadIdx.x >> 6;
    const int lane = threadIdx.x & 63;
    const int m = blockIdx.x * 4 + wid;

    const int idx = uvpos[m];
    const int ui = idx >> 3, vi = idx & 7;

    // fused entry fill: one atomic + one store per incidence
    if (lane < 8) {
        const int vp8 = vertex[m * 8 + lane];
        const int role = (lane == ui || lane == vi) ? 0 : 1;
        const int slot = atomicAdd(cur + vp8, 1);
        if (slot < ECAP) entries[(long)vp8 * ECAP + slot] = (m << 1) | role;
    }

    float S0 = 0.f, S1 = 0.f, U0 = 0.f, U1 = 0.f, V0 = 0.f, V1 = 0.f;
    #pragma unroll
    for (int p = 0; p < 8; ++p) {
        const int vp = vertex[m * 8 + p];
        const float di = rsqrtf(deg[vp]);
        const __hip_bfloat162 y2 =
            ((const __hip_bfloat162*)(Ybf + (long)vp * 128))[lane];
        const float r0 = __bfloat162float(y2.x) * di;
        const float r1 = __bfloat162float(y2.y) * di;
        S0 += r0; S1 += r1;
        if (p == ui) { U0 = r0; U1 = r1; }
        if (p == vi) { V0 = r0; V1 = r1; }
    }
    __hip_bfloat162 s2, p2;
    s2.x = __float2bfloat16(WMED * S0);
    s2.y = __float2bfloat16(WMED * S1);
    p2.x = __float2bfloat16(WMED * (U0 + V0));
    p2.y = __float2bfloat16(WMED * (U1 + V1));
    SP[(long)(2 * m) * 64 + lane] = s2;        // S row
    SP[(long)(2 * m + 1) * 64 + lane] = p2;    // P row
}

// ---------------- K5: per-vertex gather: one bf16 row per incidence --------
// R11: 8-wide chunks. R14: fixed-slot entries -- row base is i*ECAP, length
// cnt[i] (clamped to ECAP); one coalesced 128B entry-row load per vertex.
__global__ __launch_bounds__(256) void k_gather(const float* __restrict__ Y,
                                                const float* __restrict__ deg,
                                                const int* __restrict__ cnt,
                                                const int* __restrict__ entries,
                                                const __hip_bfloat162* __restrict__ SP,
                                                float* __restrict__ out) {
    const int wid = threadIdx.x >> 6;
    const int lane = threadIdx.x & 63;
    const int i = blockIdx.x * 4 + wid;

    int degc = cnt[i];
    if (degc > ECAP) degc = ECAP;          // defensive (P ~ 1e-17)
    const long base = (long)i * ECAP;
    const int tl = (lane < degc) ? entries[base + lane] : 0;

    const float din = rsqrtf(deg[i]);
    const float2 y = *(const float2*)(Y + (long)i * 128 + lane * 2);
    const float xs0 = y.x * din;
    const float xs1 = y.y * din;

    float a0 = 0.f, a1 = 0.f;
    float fnuv = 0.f;

    for (int e = 0; e < degc; e += 8) {
        const int j1 = (e + 1 < degc) ? e + 1 : e;
        const int j2 = (e + 2 < degc) ? e + 2 : e;
        const int j3 = (e + 3 < degc) ? e + 3 : e;
        const int j4 = (e + 4 < degc) ? e + 4 : e;
        const int j5 = (e + 5 < degc) ? e + 5 : e;
        const int j6 = (e + 6 < degc) ? e + 6 : e;
        const int j7 = (e + 7 < degc) ? e + 7 : e;
        const float m1 = (e + 1 < degc) ? 1.f : 0.f;
        const float m2 = (e + 2 < degc) ? 1.f : 0.f;
        const float m3 = (e + 3 < degc) ? 1.f : 0.f;
        const float m4 = (e + 4 < degc) ? 1.f : 0.f;
        const float m5 = (e + 5 < degc) ? 1.f : 0.f;
        const float m6 = (e + 6 < degc) ? 1.f : 0.f;
        const float m7 = (e + 7 < degc) ? 1.f : 0.f;
        const int t0 = __shfl(tl, e);
        const int t1 = __shfl(tl, j1);
        const int t2 = __shfl(tl, j2);
        const int t3 = __shfl(tl, j3);
        const int t4 = __shfl(tl, j4);
        const int t5 = __shfl(tl, j5);
        const int t6 = __shfl(tl, j6);
        const int t7 = __shfl(tl, j7);
        // 8 independent 256B row loads issue back-to-back
        const __hip_bfloat162 T0 = SP[(long)t0 * 64 + lane];
        const __hip_bfloat162 T1 = SP[(long)t1 * 64 + lane];
        const __hip_bfloat162 T2 = SP[(long)t2 * 64 + lane];
        const __hip_bfloat162 T3 = SP[(long)t3 * 64 + lane];
        const __hip_bfloat162 T4 = SP[(long)t4 * 64 + lane];
        const __hip_bfloat162 T5 = SP[(long)t5 * 64 + lane];
        const __hip_bfloat162 T6 = SP[(long)t6 * 64 + lane];
        const __hip_bfloat162 T7 = SP[(long)t7 * 64 + lane];
        fnuv += (float)((t0 & 1) ^ 1) + m1 * (float)((t1 & 1) ^ 1)
              + m2 * (float)((t2 & 1) ^ 1) + m3 * (float)((t3 & 1) ^ 1)
              + m4 * (float)((t4 & 1) ^ 1) + m5 * (float)((t5 & 1) ^ 1)
              + m6 * (float)((t6 & 1) ^ 1) + m7 * (float)((t7 & 1) ^ 1);
        a0 += __bfloat162float(T0.x) + m1 * __bfloat162float(T1.x)
            + m2 * __bfloat162float(T2.x) + m3 * __bfloat162float(T3.x)
            + m4 * __bfloat162float(T4.x) + m5 * __bfloat162float(T5.x)
            + m6 * __bfloat162float(T6.x) + m7 * __bfloat162float(T7.x);
        a1 += __bfloat162float(T0.y) + m1 * __bfloat162float(T1.y)
            + m2 * __bfloat162float(T2.y) + m3 * __bfloat162float(T3.y)
            + m4 * __bfloat162float(T4.y) + m5 * __bfloat162float(T5.y)
            + m6 * __bfloat162float(T6.y) + m7 * __bfloat162float(T7.y);
    }

    const float self = 1.0f - WMED * fnuv;
    a0 = fmaf(self, xs0, a0);
    a1 = fmaf(self, xs1, a1);
    float2 o;
    o.x = fmaxf(a0 * din, 0.0f);
    o.y = fmaxf(a1 * din, 0.0f);
    *(float2*)(out + (long)i * 128 + lane * 2) = o;
}

extern "C" void kernel_launch(void* const* d_in, const int* in_sizes, int n_in,
                              void* d_out, int out_size, void* d_ws, size_t ws_size,
                              hipStream_t stream) {
    const float* X      = (const float*)d_in[0];   // [N,128]
    const int*   vertex = (const int*)d_in[1];     // [M*8]
    // d_in[2] = edges (repeat(arange(M),8)) -- unused
    const float* W      = (const float*)d_in[3];   // [128,128]
    const float* bias   = (const float*)d_in[4];   // [128]
    float* out = (float*)d_out;                    // [N,128]

    // workspace: Y[N*128] f32 | Ybf[N*128] bf16 | SP[2M*128] bf16 | deg[N] |
    //            uvpos[M] | cnt[N] | cur[N] | entries[N*ECAP]
    float* Y              = (float*)d_ws;
    __hip_bfloat16* Ybf   = (__hip_bfloat16*)(Y + (long)NV * 128);
    __hip_bfloat162* SP   = (__hip_bfloat162*)(Ybf + (long)NV * 128);
    float* deg            = (float*)((__hip_bfloat16*)SP + (long)2 * ME * 128);
    int*   uvpos          = (int*)(deg + NV);
    int*   cnt            = uvpos + ME;
    int*   cur            = cnt + NV;
    int*   entries        = cur + NV;

    k_gemm <<<(NV + 255) / 256, 512, 0, stream>>>(X, W, bias, Y, Ybf, cnt, cur, deg);
    k_edge <<<ME / 4, 256, 0, stream>>>(Y, vertex, uvpos, cnt, deg);
    k_sp   <<<ME / 4, 256, 0, stream>>>(Ybf, vertex, uvpos, deg, cur, entries, SP);
    k_gather<<<NV / 4, 256, 0, stream>>>(Y, deg, cnt, entries, SP, out);
}

// Round 15
// 248.563 us; speedup vs baseline: 1.0370x; 1.0370x over previous
//
#include <hip/hip_runtime.h>
#include <hip/hip_bf16.h>

// Problem constants (HyperGCNConv: N=100000, M=50000, K=8, DIN=DOUT=128)
#define NV 100000
#define ME 50000
#define NINC (ME * 8)                     // 400000 incidences
#define NBLK ((NV + 255) / 256)           // 391 init blocks
#define NRBG ((NV + 127) / 128)           // 782 gemm row-blocks (128 rows each)
#define ECAP 32                           // fixed entry slots per vertex (P(deg>32)~1e-17)
constexpr float WMED = 1.0f / 13.0f;      // 1/(2K-3), K=8

typedef __attribute__((ext_vector_type(8))) short bf16x8;   // MFMA A/B frag
typedef __attribute__((ext_vector_type(4))) float f32x4;    // MFMA C/D frag

static __device__ inline void cvt_split8(const float4& a, const float4& b,
                                         bf16x8& hi, bf16x8& lo) {
    const float v[8] = {a.x, a.y, a.z, a.w, b.x, b.y, b.z, b.w};
    #pragma unroll
    for (int j = 0; j < 8; ++j) {
        __hip_bfloat16 h = __float2bfloat16(v[j]);
        const float hf = __bfloat162float(h);
        __hip_bfloat16 l = __float2bfloat16(v[j] - hf);
        union { __hip_bfloat16 b; short s; } uh{h}, ul{l};
        hi[j] = uh.s;
        lo[j] = ul.s;
    }
}

// ---------------- K0: one-off W split + workspace init ---------------------
// R15: restored (R14's in-gemm staging was the regression: journal error --
// 44.2us belonged to the Wg-prestaged column-split gemm, not in-LDS staging).
// Wg frag index = mat*2048 + cb*1024 + (s*4+gp)*64 + (qq*16 + m); 16B frags.
// Grid NBLK: all threads init cnt/cur/deg; first 16384 also split W.
__global__ __launch_bounds__(256) void k_winit(const float* __restrict__ W,
                                               short* __restrict__ Wg,
                                               int* __restrict__ cnt,
                                               int* __restrict__ cur,
                                               float* __restrict__ deg) {
    const int i = blockIdx.x * 256 + threadIdx.x;
    if (i < NV) { cnt[i] = 0; cur[i] = 0; deg[i] = 1.0f; }
    if (i < 16384) {
        const int k = i >> 7;          // row 0..127
        const int c = i & 127;         // col 0..127
        const float w = W[i];
        __hip_bfloat16 h = __float2bfloat16(w);
        const float hf = __bfloat162float(h);
        __hip_bfloat16 l = __float2bfloat16(w - hf);
        const int cb = c >> 6, gp = (c >> 4) & 3, m = c & 15;
        const int s = k >> 5, qq = (k >> 3) & 3, j = k & 7;
        const int base = cb * 1024 + (s * 4 + gp) * 64 + qq * 16 + m;
        union { __hip_bfloat16 b; short s; } uh{h}, ul{l};
        Wg[(long)base * 8 + j] = uh.s;                    // mat 0 (Wh)
        Wg[(long)(2048 + base) * 8 + j] = ul.s;           // mat 1 (Wl)
    }
}

// ---------------- K1: Y = X @ W + b via split-bf16 MFMA ----------------
// R6 structure restored (plateau-verified <=48us): LDS-FREE, Wg hot in L2,
// B-frags read directly (16B/lane coalesced), no barrier, 2-stage A
// prefetch, g-innermost epilogue. 256 thr, 128 rows x 64 cols per block.
__global__ __launch_bounds__(256, 4) void k_gemm(const float* __restrict__ X,
                                                 const uint4* __restrict__ Wg,
                                                 const float* __restrict__ bias,
                                                 float* __restrict__ Y,
                                                 __hip_bfloat16* __restrict__ Ybf) {
    const int t = threadIdx.x;
    const int wv = t >> 6;         // wave 0..3 -> rows 32wv..32wv+31
    const int L  = t & 63;
    const int m  = L & 15;         // A row sel / B,C col sel
    const int q  = L >> 4;         // k-quad / C row-quad

    const int rb = blockIdx.x >> 1;       // row block (128 rows)
    const int cb = blockIdx.x & 1;        // col block (64 cols)

    const int row_base = rb * 128 + wv * 32;
    int r0 = row_base + m;      if (r0 > NV - 1) r0 = NV - 1;
    int r1 = row_base + 16 + m; if (r1 > NV - 1) r1 = NV - 1;
    const float* p0 = X + (long)r0 * 128 + q * 8;
    const float* p1 = X + (long)r1 * 128 + q * 8;

    const bf16x8* Whf = (const bf16x8*)Wg + cb * 1024;          // hi frags
    const bf16x8* Wlf = (const bf16x8*)Wg + 2048 + cb * 1024;   // lo frags

    f32x4 acc[2][4];
    #pragma unroll
    for (int tt = 0; tt < 2; ++tt)
        #pragma unroll
        for (int g = 0; g < 4; ++g)
            acc[tt][g] = (f32x4){0.f, 0.f, 0.f, 0.f};

    // 2-stage A pipeline: prefetch s+1 while computing s
    float4 Ac0 = *(const float4*)(p0);
    float4 Ac1 = *(const float4*)(p0 + 4);
    float4 Ac2 = *(const float4*)(p1);
    float4 Ac3 = *(const float4*)(p1 + 4);

    #pragma unroll
    for (int s = 0; s < 4; ++s) {
        float4 An0, An1, An2, An3;
        if (s < 3) {
            An0 = *(const float4*)(p0 + (s + 1) * 32);
            An1 = *(const float4*)(p0 + (s + 1) * 32 + 4);
            An2 = *(const float4*)(p1 + (s + 1) * 32);
            An3 = *(const float4*)(p1 + (s + 1) * 32 + 4);
        }
        bf16x8 ah0, al0, ah1, al1;
        cvt_split8(Ac0, Ac1, ah0, al0);
        cvt_split8(Ac2, Ac3, ah1, al1);
        #pragma unroll
        for (int g = 0; g < 4; ++g) {
            const bf16x8 bh = Whf[(s * 4 + g) * 64 + L];
            const bf16x8 bl = Wlf[(s * 4 + g) * 64 + L];
            acc[0][g] = __builtin_amdgcn_mfma_f32_16x16x32_bf16(ah0, bh, acc[0][g], 0, 0, 0);
            acc[0][g] = __builtin_amdgcn_mfma_f32_16x16x32_bf16(ah0, bl, acc[0][g], 0, 0, 0);
            acc[0][g] = __builtin_amdgcn_mfma_f32_16x16x32_bf16(al0, bh, acc[0][g], 0, 0, 0);
            acc[1][g] = __builtin_amdgcn_mfma_f32_16x16x32_bf16(ah1, bh, acc[1][g], 0, 0, 0);
            acc[1][g] = __builtin_amdgcn_mfma_f32_16x16x32_bf16(ah1, bl, acc[1][g], 0, 0, 0);
            acc[1][g] = __builtin_amdgcn_mfma_f32_16x16x32_bf16(al1, bh, acc[1][g], 0, 0, 0);
        }
        if (s < 3) { Ac0 = An0; Ac1 = An1; Ac2 = An2; Ac3 = An3; }
    }

    // bias per col-group, hoisted
    float bc[4];
    #pragma unroll
    for (int g = 0; g < 4; ++g) bc[g] = bias[cb * 64 + g * 16 + m];

    // epilogue: C layout col=lane&15, row=quad*4+reg; g INNERMOST
    #pragma unroll
    for (int tt = 0; tt < 2; ++tt) {
        #pragma unroll
        for (int r = 0; r < 4; ++r) {
            const int row = row_base + tt * 16 + q * 4 + r;
            float vg[4], vn[4];
            #pragma unroll
            for (int g = 0; g < 4; ++g) {
                vg[g] = acc[tt][g][r] + bc[g];
                vn[g] = __shfl_xor(vg[g], 1);   // neighbor col (lane pair)
            }
            if (row < NV) {
                #pragma unroll
                for (int g = 0; g < 4; ++g)
                    Y[(long)row * 128 + cb * 64 + g * 16 + m] = vg[g];
                if ((L & 1) == 0) {
                    #pragma unroll
                    for (int g = 0; g < 4; ++g) {
                        __hip_bfloat162 h2;
                        h2.x = __float2bfloat16(vg[g]);
                        h2.y = __float2bfloat16(vn[g]);
                        *(__hip_bfloat162*)(Ybf + (long)row * 128 + cb * 64 + g * 16 + m) = h2;
                    }
                }
            }
        }
    }
}

// ---------------- K2: per-hyperedge argmax pair (uvpos only) ----------------
// R10 structure: random-512B-gather bound (~2.5TB/s fabric, FETCH 93MB,
// floor ~42-48us -- implementation-insensitive, verified across 4 variants).
// Fused CSR histogram (R10) + fused deg atomics (R12) ride under the gather.
__global__ __launch_bounds__(256) void k_edge(const float* __restrict__ Y,
                                              const int* __restrict__ vertex,
                                              int* __restrict__ uvpos,
                                              int* __restrict__ cnt,
                                              float* __restrict__ deg) {
    __shared__ float sF[4][8 * 132];
    const int wid = threadIdx.x >> 6;
    const int lane = threadIdx.x & 63;
    const int m = blockIdx.x * 4 + wid;
    float* F = sF[wid];

    int verts[8];
    #pragma unroll
    for (int p = 0; p < 8; ++p) verts[p] = vertex[m * 8 + p];

    // fused histogram: one atomic per incidence, hidden under the row gather
    if (lane < 8) atomicAdd(cnt + vertex[m * 8 + lane], 1);

    #pragma unroll
    for (int p = 0; p < 8; ++p) {
        const float2 v = *(const float2*)(Y + (long)verts[p] * 128 + lane * 2);
        *(float2*)(F + p * 132 + lane * 2) = v;
    }
    __syncthreads();

    const int k = lane >> 3, l = lane & 7;
    float acc = 0.0f;
    const float4* ra = (const float4*)(F + k * 132);
    const float4* rb = (const float4*)(F + l * 132);
    #pragma unroll
    for (int d4 = 0; d4 < 32; ++d4) {
        const float4 a = ra[d4], b = rb[d4];
        acc = fmaf(a.x, b.x, acc);
        acc = fmaf(a.y, b.y, acc);
        acc = fmaf(a.z, b.z, acc);
        acc = fmaf(a.w, b.w, acc);
    }
    const float sqk = __shfl(acc, k * 9);
    const float sql = __shfl(acc, l * 9);
    float v = sqk + sql - 2.0f * acc;
    int idx = lane;
    #pragma unroll
    for (int off = 32; off >= 1; off >>= 1) {
        const float ov = __shfl_xor(v, off);
        const int oi = __shfl_xor(idx, off);
        if (ov > v || (ov == v && oi < idx)) { v = ov; idx = oi; }
    }
    if (lane == 0) uvpos[m] = idx;

    // fused degree: role by POSITION (matches ref's med mask semantics)
    if (lane < 8) {
        const int ui = idx >> 3, vi = idx & 7;
        const float w = (lane == ui || lane == vi) ? (7.0f * WMED) : (2.0f * WMED);
        atomicAdd(deg + vertex[m * 8 + lane], w);
    }
}

// ---------------- K4: per-edge w*S,w*P rows + fixed-slot entry fill --------
// R14 (kept): entries are fixed-slot [NV][ECAP] -- no scan, no rowptr.
// Lanes 0..7 write this edge's 8 entries via atomic cursor `cur`, hidden
// under the Ybf random-gather latency (R10/R12/R13 precedent).
__global__ __launch_bounds__(256) void k_sp(const __hip_bfloat16* __restrict__ Ybf,
                                            const int* __restrict__ vertex,
                                            const int* __restrict__ uvpos,
                                            const float* __restrict__ deg,
                                            int* __restrict__ cur,
                                            int* __restrict__ entries,
                                            __hip_bfloat162* __restrict__ SP) {
    const int wid = threadIdx.x >> 6;
    const int lane = threadIdx.x & 63;
    const int m = blockIdx.x * 4 + wid;

    const int idx = uvpos[m];
    const int ui = idx >> 3, vi = idx & 7;

    // fused entry fill: one atomic + one store per incidence
    if (lane < 8) {
        const int vp8 = vertex[m * 8 + lane];
        const int role = (lane == ui || lane == vi) ? 0 : 1;
        const int slot = atomicAdd(cur + vp8, 1);
        if (slot < ECAP) entries[(long)vp8 * ECAP + slot] = (m << 1) | role;
    }

    float S0 = 0.f, S1 = 0.f, U0 = 0.f, U1 = 0.f, V0 = 0.f, V1 = 0.f;
    #pragma unroll
    for (int p = 0; p < 8; ++p) {
        const int vp = vertex[m * 8 + p];
        const float di = rsqrtf(deg[vp]);
        const __hip_bfloat162 y2 =
            ((const __hip_bfloat162*)(Ybf + (long)vp * 128))[lane];
        const float r0 = __bfloat162float(y2.x) * di;
        const float r1 = __bfloat162float(y2.y) * di;
        S0 += r0; S1 += r1;
        if (p == ui) { U0 = r0; U1 = r1; }
        if (p == vi) { V0 = r0; V1 = r1; }
    }
    __hip_bfloat162 s2, p2;
    s2.x = __float2bfloat16(WMED * S0);
    s2.y = __float2bfloat16(WMED * S1);
    p2.x = __float2bfloat16(WMED * (U0 + V0));
    p2.y = __float2bfloat16(WMED * (U1 + V1));
    SP[(long)(2 * m) * 64 + lane] = s2;        // S row
    SP[(long)(2 * m + 1) * 64 + lane] = p2;    // P row
}

// ---------------- K5: per-vertex gather: one bf16 row per incidence --------
// R11: 8-wide chunks. R14 (kept): fixed-slot entries -- row base i*ECAP,
// length cnt[i] (clamped); one coalesced 128B entry-row load per vertex.
__global__ __launch_bounds__(256) void k_gather(const float* __restrict__ Y,
                                                const float* __restrict__ deg,
                                                const int* __restrict__ cnt,
                                                const int* __restrict__ entries,
                                                const __hip_bfloat162* __restrict__ SP,
                                                float* __restrict__ out) {
    const int wid = threadIdx.x >> 6;
    const int lane = threadIdx.x & 63;
    const int i = blockIdx.x * 4 + wid;

    int degc = cnt[i];
    if (degc > ECAP) degc = ECAP;          // defensive (P ~ 1e-17)
    const long base = (long)i * ECAP;
    const int tl = (lane < degc) ? entries[base + lane] : 0;

    const float din = rsqrtf(deg[i]);
    const float2 y = *(const float2*)(Y + (long)i * 128 + lane * 2);
    const float xs0 = y.x * din;
    const float xs1 = y.y * din;

    float a0 = 0.f, a1 = 0.f;
    float fnuv = 0.f;

    for (int e = 0; e < degc; e += 8) {
        const int j1 = (e + 1 < degc) ? e + 1 : e;
        const int j2 = (e + 2 < degc) ? e + 2 : e;
        const int j3 = (e + 3 < degc) ? e + 3 : e;
        const int j4 = (e + 4 < degc) ? e + 4 : e;
        const int j5 = (e + 5 < degc) ? e + 5 : e;
        const int j6 = (e + 6 < degc) ? e + 6 : e;
        const int j7 = (e + 7 < degc) ? e + 7 : e;
        const float m1 = (e + 1 < degc) ? 1.f : 0.f;
        const float m2 = (e + 2 < degc) ? 1.f : 0.f;
        const float m3 = (e + 3 < degc) ? 1.f : 0.f;
        const float m4 = (e + 4 < degc) ? 1.f : 0.f;
        const float m5 = (e + 5 < degc) ? 1.f : 0.f;
        const float m6 = (e + 6 < degc) ? 1.f : 0.f;
        const float m7 = (e + 7 < degc) ? 1.f : 0.f;
        const int t0 = __shfl(tl, e);
        const int t1 = __shfl(tl, j1);
        const int t2 = __shfl(tl, j2);
        const int t3 = __shfl(tl, j3);
        const int t4 = __shfl(tl, j4);
        const int t5 = __shfl(tl, j5);
        const int t6 = __shfl(tl, j6);
        const int t7 = __shfl(tl, j7);
        // 8 independent 256B row loads issue back-to-back
        const __hip_bfloat162 T0 = SP[(long)t0 * 64 + lane];
        const __hip_bfloat162 T1 = SP[(long)t1 * 64 + lane];
        const __hip_bfloat162 T2 = SP[(long)t2 * 64 + lane];
        const __hip_bfloat162 T3 = SP[(long)t3 * 64 + lane];
        const __hip_bfloat162 T4 = SP[(long)t4 * 64 + lane];
        const __hip_bfloat162 T5 = SP[(long)t5 * 64 + lane];
        const __hip_bfloat162 T6 = SP[(long)t6 * 64 + lane];
        const __hip_bfloat162 T7 = SP[(long)t7 * 64 + lane];
        fnuv += (float)((t0 & 1) ^ 1) + m1 * (float)((t1 & 1) ^ 1)
              + m2 * (float)((t2 & 1) ^ 1) + m3 * (float)((t3 & 1) ^ 1)
              + m4 * (float)((t4 & 1) ^ 1) + m5 * (float)((t5 & 1) ^ 1)
              + m6 * (float)((t6 & 1) ^ 1) + m7 * (float)((t7 & 1) ^ 1);
        a0 += __bfloat162float(T0.x) + m1 * __bfloat162float(T1.x)
            + m2 * __bfloat162float(T2.x) + m3 * __bfloat162float(T3.x)
            + m4 * __bfloat162float(T4.x) + m5 * __bfloat162float(T5.x)
            + m6 * __bfloat162float(T6.x) + m7 * __bfloat162float(T7.x);
        a1 += __bfloat162float(T0.y) + m1 * __bfloat162float(T1.y)
            + m2 * __bfloat162float(T2.y) + m3 * __bfloat162float(T3.y)
            + m4 * __bfloat162float(T4.y) + m5 * __bfloat162float(T5.y)
            + m6 * __bfloat162float(T6.y) + m7 * __bfloat162float(T7.y);
    }

    const float self = 1.0f - WMED * fnuv;
    a0 = fmaf(self, xs0, a0);
    a1 = fmaf(self, xs1, a1);
    float2 o;
    o.x = fmaxf(a0 * din, 0.0f);
    o.y = fmaxf(a1 * din, 0.0f);
    *(float2*)(out + (long)i * 128 + lane * 2) = o;
}

extern "C" void kernel_launch(void* const* d_in, const int* in_sizes, int n_in,
                              void* d_out, int out_size, void* d_ws, size_t ws_size,
                              hipStream_t stream) {
    const float* X      = (const float*)d_in[0];   // [N,128]
    const int*   vertex = (const int*)d_in[1];     // [M*8]
    // d_in[2] = edges (repeat(arange(M),8)) -- unused
    const float* W      = (const float*)d_in[3];   // [128,128]
    const float* bias   = (const float*)d_in[4];   // [128]
    float* out = (float*)d_out;                    // [N,128]

    // workspace: Y[N*128] f32 | Ybf[N*128] bf16 | SP[2M*128] bf16 | deg[N] |
    //            uvpos[M] | cnt[N] | cur[N] | entries[N*ECAP] | Wg (64KB)
    float* Y              = (float*)d_ws;
    __hip_bfloat16* Ybf   = (__hip_bfloat16*)(Y + (long)NV * 128);
    __hip_bfloat162* SP   = (__hip_bfloat162*)(Ybf + (long)NV * 128);
    float* deg            = (float*)((__hip_bfloat16*)SP + (long)2 * ME * 128);
    int*   uvpos          = (int*)(deg + NV);
    int*   cnt            = uvpos + ME;
    int*   cur            = cnt + NV;
    int*   entries        = cur + NV;
    char*  pW             = (char*)(entries + (long)NV * ECAP);
    uint4* Wg             = (uint4*)(((uintptr_t)pW + 15) & ~(uintptr_t)15);

    k_winit<<<NBLK, 256, 0, stream>>>(W, (short*)Wg, cnt, cur, deg);
    k_gemm <<<NRBG * 2, 256, 0, stream>>>(X, Wg, bias, Y, Ybf);
    k_edge <<<ME / 4, 256, 0, stream>>>(Y, vertex, uvpos, cnt, deg);
    k_sp   <<<ME / 4, 256, 0, stream>>>(Ybf, vertex, uvpos, deg, cur, entries, SP);
    k_gather<<<NV / 4, 256, 0, stream>>>(Y, deg, cnt, entries, SP, out);
}